// Round 2
// baseline (1242.312 us; speedup 1.0000x reference)
//
#include <hip/hip_runtime.h>
#include <cstdint>

// EarthAttention3D on gfx950 — f16 MFMA path, round 2.
// R1 post-mortem: qkv_gemm FETCH 471MB (ideal 106) — 9 col-blocks re-read A.
// R2: 1-D grid over rows; col-loop in-kernel; A frags register-resident
// (read once, fp32->f16 converted in-reg, cvt kernel deleted); B staged per
// 64-col tile in LDS k-major slabs (1040B stride, bank-even for writes+reads).

typedef _Float16 f16;
typedef _Float16 f16x8 __attribute__((ext_vector_type(8)));
typedef float f32x4 __attribute__((ext_vector_type(4)));

#define NW_ 64
#define HEADS_ 12
#define DIM_ 384
#define BATCH_ 15
#define NTOK_ 144
#define HD_ 32
#define MTOK_ (BATCH_*NW_*NTOK_)   // 138240
#define NWH_ (BATCH_*NW_*HEADS_)   // 11520
#define BSLAB 520                  // f16 units per k-slab: 64 chunks*16B + 16B pad

__device__ __forceinline__ f32x4 fzero4() {
    f32x4 z; z[0]=0.f; z[1]=0.f; z[2]=0.f; z[3]=0.f; return z;
}

// src [K][N] fp32 -> dst [N][K] f16  (coalesced writes)
__global__ void transpose_cvt(const float* __restrict__ src, f16* __restrict__ dst, int K, int N) {
    int i = blockIdx.x * blockDim.x + threadIdx.x;
    if (i >= K*N) return;
    int n = i / K;
    int k = i - n*K;
    dst[i] = (f16)src[k*N + n];
}

// ---------------- QKV GEMM ----------------
// A: x fp32 [MTOK][384] (converted in-reg); Bt: wt_qkv f16 [1152][384].
// Grid 1080 (rows/128); wave owns 32 rows; loops 18 col-tiles of 64.
__global__ __launch_bounds__(256, 2) void qkv_gemm(
    const float* __restrict__ X, const f16* __restrict__ Bt,
    const float* __restrict__ bias,
    f16* __restrict__ qws, f16* __restrict__ kws, f16* __restrict__ vws)
{
    __shared__ __align__(16) f16 Bsm[48 * BSLAB];   // 49,920 B
    const int tid  = threadIdx.x;
    const int lane = tid & 63;
    const int wave = tid >> 6;
    const int l15  = lane & 15;
    const int quad = lane >> 4;
    const int row0 = blockIdx.x * 128 + wave * 32;  // wave-exclusive 32 rows

    // A fragments, whole K: af[i][kt] rows row0+i*16+l15, k = kt*32+quad*8..+8
    f16x8 af[2][12];
    #pragma unroll
    for (int i = 0; i < 2; ++i) {
        const float* rp = &X[(size_t)(row0 + i*16 + l15)*DIM_ + quad*8];
        #pragma unroll
        for (int kt = 0; kt < 12; ++kt) {
            float4 v0 = *(const float4*)(rp + kt*32);
            float4 v1 = *(const float4*)(rp + kt*32 + 4);
            f16x8 a;
            a[0]=(f16)v0.x; a[1]=(f16)v0.y; a[2]=(f16)v0.z; a[3]=(f16)v0.w;
            a[4]=(f16)v1.x; a[5]=(f16)v1.y; a[6]=(f16)v1.z; a[7]=(f16)v1.w;
            af[i][kt] = a;
        }
    }

    for (int ct = 0; ct < 18; ++ct) {
        __syncthreads();  // previous tile's LDS reads done
        const f16* bsrc = Bt + (size_t)ct*64*DIM_;
        #pragma unroll
        for (int s = 0; s < 12; ++s) {
            int flat = tid + s*256;       // 16B chunk id 0..3071
            int r = flat / 48;            // Bt row (= output col) 0..63
            int c = flat - r*48;          // k-chunk 0..47
            f16x8 v = *(const f16x8*)&bsrc[(size_t)r*DIM_ + c*8];
            *(f16x8*)&Bsm[c*BSLAB + r*8] = v;
        }
        __syncthreads();

        f32x4 acc[2][4];
        #pragma unroll
        for (int i = 0; i < 2; ++i)
            #pragma unroll
            for (int j = 0; j < 4; ++j) acc[i][j] = fzero4();

        #pragma unroll
        for (int kt = 0; kt < 12; ++kt) {
            f16x8 bf[4];
            #pragma unroll
            for (int j = 0; j < 4; ++j)
                bf[j] = *(const f16x8*)&Bsm[(kt*4 + quad)*BSLAB + (j*16 + l15)*8];
            #pragma unroll
            for (int i = 0; i < 2; ++i)
                #pragma unroll
                for (int j = 0; j < 4; ++j)
                    acc[i][j] = __builtin_amdgcn_mfma_f32_16x16x32_f16(af[i][kt], bf[j], acc[i][j], 0, 0, 0);
        }

        // epilogue: col -> (which, h, d); row -> (bw, n)
        const int which = ct / 6;             // 64-col tiles never straddle q/k/v
        const int cb = ct*64 - which*DIM_;
        #pragma unroll
        for (int j = 0; j < 4; ++j) {
            int col = ct*64 + j*16 + l15;
            float bq = bias[col];
            int rem = cb + j*16 + l15;
            int h = rem >> 5, d = rem & 31;
            #pragma unroll
            for (int i = 0; i < 2; ++i) {
                int rowb = row0 + i*16 + quad*4;
                #pragma unroll
                for (int r = 0; r < 4; ++r) {
                    int row = rowb + r;
                    int bw  = row / NTOK_;
                    int n   = row - bw*NTOK_;
                    int head = bw*HEADS_ + h;
                    f16 hv = (f16)(acc[i][j][r] + bq);
                    if (which == 0)      qws[(size_t)head*NTOK_*HD_ + n*HD_ + d] = hv;
                    else if (which == 1) kws[(size_t)head*NTOK_*HD_ + n*HD_ + d] = hv;
                    else                 vws[(size_t)head*HD_*NTOK_ + d*NTOK_ + n] = hv;
                }
            }
        }
    }
}

// ---------------- fused attention (unchanged from R1) ----------------
__global__ __launch_bounds__(576) void attention(
    const f16* __restrict__ qws, const f16* __restrict__ kws, const f16* __restrict__ vws,
    const float* __restrict__ bias_table, const int* __restrict__ pos_idx,
    const float* __restrict__ mask, f16* __restrict__ ows)
{
    constexpr int KPAD = 40;   // Ksm row stride (f16)
    constexpr int VPAD = 168;  // Vt / P row stride (f16), 160 used
    __shared__ __align__(16) char smem[10752 + 48384];
    f16* Vt  = (f16*)smem;            // [32][168]
    f16* Ksm = (f16*)(smem + 10752);  // [144][40]
    f16* Pst = (f16*)(smem + 10752);  // [9][16][168] overlays Ksm

    const int tid  = threadIdx.x;
    const int lane = tid & 63;
    const int wv   = tid >> 6;    // 0..8: Q row tile
    const int l15  = lane & 15;
    const int quad = lane >> 4;

    const int wh = blockIdx.x;
    const int w  = wh / HEADS_;
    const int h  = wh - w*HEADS_;

    float brg[9][4];
    #pragma unroll
    for (int j = 0; j < 9; ++j) {
        int m = j*16 + l15;
        #pragma unroll
        for (int r = 0; r < 4; ++r) {
            int n = wv*16 + quad*4 + r;
            int idx = pos_idx[n*NTOK_ + m];
            brg[j][r] = bias_table[(size_t)idx*(NW_*HEADS_) + w*HEADS_ + h];
        }
    }

    if (tid < 64) {
        int d = tid >> 1, m0 = 144 + (tid & 1)*8;
        uint4 z = {0u,0u,0u,0u};
        *(uint4*)&Vt[d*VPAD + m0] = z;
    }

    const float scale = 0.17677669529663687f;  // 32^-0.5

    for (int b = 0; b < BATCH_; ++b) {
        const int bwh = (b*NW_ + w)*HEADS_ + h;
        const f16* qh = qws + (size_t)bwh*NTOK_*HD_;
        const f16* kh = kws + (size_t)bwh*NTOK_*HD_;
        const f16* vh = vws + (size_t)bwh*HD_*NTOK_;

        __syncthreads();
        {
            int flat = tid*8;
            int n = flat >> 5, d = flat & 31;
            *(uint4*)&Ksm[n*KPAD + d] = *(const uint4*)&kh[flat];
            int dv = flat / NTOK_;
            int mv = flat - dv*NTOK_;
            *(uint4*)&Vt[dv*VPAD + mv] = *(const uint4*)&vh[flat];
        }
        int nq = wv*16 + l15;
        f16x8 qf = *(const f16x8*)&qh[nq*HD_ + quad*8];
        __syncthreads();

        f32x4 sfr[9];
        #pragma unroll
        for (int j = 0; j < 9; ++j) {
            f16x8 kf = *(const f16x8*)&Ksm[(j*16 + l15)*KPAD + quad*8];
            sfr[j] = __builtin_amdgcn_mfma_f32_16x16x32_f16(qf, kf, fzero4(), 0, 0, 0);
        }
        __syncthreads();

        float p[9][4], rmax[4], rsum[4];
        #pragma unroll
        for (int r = 0; r < 4; ++r) rmax[r] = -1e30f;
        const float* mrow = mask + (size_t)b*NTOK_*NTOK_;
        #pragma unroll
        for (int j = 0; j < 9; ++j) {
            int m = j*16 + l15;
            #pragma unroll
            for (int r = 0; r < 4; ++r) {
                int n = wv*16 + quad*4 + r;
                float s = sfr[j][r]*scale + brg[j][r] + mrow[n*NTOK_ + m];
                p[j][r] = s;
                rmax[r] = fmaxf(rmax[r], s);
            }
        }
        #pragma unroll
        for (int r = 0; r < 4; ++r) {
            float v = rmax[r];
            #pragma unroll
            for (int off = 1; off < 16; off <<= 1)
                v = fmaxf(v, __shfl_xor(v, off, 64));
            rmax[r] = v;
        }
        #pragma unroll
        for (int r = 0; r < 4; ++r) rsum[r] = 0.f;
        #pragma unroll
        for (int j = 0; j < 9; ++j)
            #pragma unroll
            for (int r = 0; r < 4; ++r) {
                float e = __expf(p[j][r] - rmax[r]);
                p[j][r] = e;
                rsum[r] += e;
            }
        #pragma unroll
        for (int r = 0; r < 4; ++r) {
            float v = rsum[r];
            #pragma unroll
            for (int off = 1; off < 16; off <<= 1)
                v += __shfl_xor(v, off, 64);
            rsum[r] = 1.0f / v;
        }

        f16* Pw = Pst + wv*16*VPAD;
        #pragma unroll
        for (int j = 0; j < 9; ++j) {
            int m = j*16 + l15;
            #pragma unroll
            for (int r = 0; r < 4; ++r)
                Pw[(quad*4 + r)*VPAD + m] = (f16)(p[j][r]*rsum[r]);
        }
        if (lane < 32) {
            int row = lane >> 1, m0 = 144 + (lane & 1)*8;
            uint4 z = {0u,0u,0u,0u};
            *(uint4*)&Pw[row*VPAD + m0] = z;
        }

        f32x4 o0 = fzero4(), o1 = fzero4();
        #pragma unroll
        for (int s = 0; s < 5; ++s) {
            f16x8 pa = *(const f16x8*)&Pw[l15*VPAD + s*32 + quad*8];
            f16x8 v0 = *(const f16x8*)&Vt[l15*VPAD + s*32 + quad*8];
            f16x8 v1 = *(const f16x8*)&Vt[(16 + l15)*VPAD + s*32 + quad*8];
            o0 = __builtin_amdgcn_mfma_f32_16x16x32_f16(pa, v0, o0, 0, 0, 0);
            o1 = __builtin_amdgcn_mfma_f32_16x16x32_f16(pa, v1, o1, 0, 0, 0);
        }

        const int bw = b*NW_ + w;
        #pragma unroll
        for (int r = 0; r < 4; ++r) {
            int n = wv*16 + quad*4 + r;
            size_t base = ((size_t)bw*NTOK_ + n)*DIM_ + h*HD_;
            ows[base + l15]      = (f16)o0[r];
            ows[base + 16 + l15] = (f16)o1[r];
        }
    }
}

// ---------------- proj GEMM ----------------
// A: o_f16 [MTOK][384]; Bt: wt_proj f16 [384][384]; out fp32 [MTOK][384].
// Same structure as qkv_gemm: grid 1080, 6 col-tiles in-kernel.
__global__ __launch_bounds__(256, 2) void proj_gemm(
    const f16* __restrict__ A, const f16* __restrict__ Bt,
    const float* __restrict__ bias, float* __restrict__ out)
{
    __shared__ __align__(16) f16 Bsm[48 * BSLAB];
    const int tid  = threadIdx.x;
    const int lane = tid & 63;
    const int wave = tid >> 6;
    const int l15  = lane & 15;
    const int quad = lane >> 4;
    const int row0 = blockIdx.x * 128 + wave * 32;

    f16x8 af[2][12];
    #pragma unroll
    for (int i = 0; i < 2; ++i) {
        const f16* rp = &A[(size_t)(row0 + i*16 + l15)*DIM_ + quad*8];
        #pragma unroll
        for (int kt = 0; kt < 12; ++kt)
            af[i][kt] = *(const f16x8*)(rp + kt*32);
    }

    for (int ct = 0; ct < 6; ++ct) {
        __syncthreads();
        const f16* bsrc = Bt + (size_t)ct*64*DIM_;
        #pragma unroll
        for (int s = 0; s < 12; ++s) {
            int flat = tid + s*256;
            int r = flat / 48;
            int c = flat - r*48;
            f16x8 v = *(const f16x8*)&bsrc[(size_t)r*DIM_ + c*8];
            *(f16x8*)&Bsm[c*BSLAB + r*8] = v;
        }
        __syncthreads();

        f32x4 acc[2][4];
        #pragma unroll
        for (int i = 0; i < 2; ++i)
            #pragma unroll
            for (int j = 0; j < 4; ++j) acc[i][j] = fzero4();

        #pragma unroll
        for (int kt = 0; kt < 12; ++kt) {
            f16x8 bf[4];
            #pragma unroll
            for (int j = 0; j < 4; ++j)
                bf[j] = *(const f16x8*)&Bsm[(kt*4 + quad)*BSLAB + (j*16 + l15)*8];
            #pragma unroll
            for (int i = 0; i < 2; ++i)
                #pragma unroll
                for (int j = 0; j < 4; ++j)
                    acc[i][j] = __builtin_amdgcn_mfma_f32_16x16x32_f16(af[i][kt], bf[j], acc[i][j], 0, 0, 0);
        }

        #pragma unroll
        for (int j = 0; j < 4; ++j) {
            int col = ct*64 + j*16 + l15;
            float bp = bias[col];
            #pragma unroll
            for (int i = 0; i < 2; ++i) {
                int rowb = row0 + i*16 + quad*4;
                #pragma unroll
                for (int r = 0; r < 4; ++r)
                    out[(size_t)(rowb + r)*DIM_ + col] = acc[i][j][r] + bp;
            }
        }
    }
}

// ---------------- launcher ----------------
extern "C" void kernel_launch(void* const* d_in, const int* in_sizes, int n_in,
                              void* d_out, int out_size, void* d_ws, size_t ws_size,
                              hipStream_t stream)
{
    const float* x      = (const float*)d_in[0];
    const float* mask   = (const float*)d_in[1];
    const float* w_qkv  = (const float*)d_in[2];
    const float* b_qkv  = (const float*)d_in[3];
    const float* w_proj = (const float*)d_in[4];
    const float* b_proj = (const float*)d_in[5];
    const float* btab   = (const float*)d_in[6];
    const int*   pidx   = (const int*)d_in[7];
    float* out = (float*)d_out;

    constexpr size_t OWS_B = (size_t)MTOK_*DIM_*2;        // 106,168,320
    constexpr size_t WTQ_B = (size_t)1152*384*2;          // 884,736
    constexpr size_t WTP_B = (size_t)384*384*2;           // 294,912
    constexpr size_t HEAD_B = (size_t)NWH_*NTOK_*HD_*2;   // 106,168,320

    char* ws = (char*)d_ws;
    f16* ows = (f16*)ws;
    f16* wtq = (f16*)(ws + OWS_B);
    f16* wtp = (f16*)(ws + OWS_B + WTQ_B);
    f16* qws = (f16*)(ws + OWS_B + WTQ_B + WTP_B);
    f16* kws = (f16*)((char*)qws + HEAD_B);
    f16* vws = (f16*)((char*)kws + HEAD_B);

    transpose_cvt<<<(384*1152 + 255)/256, 256, 0, stream>>>(w_qkv, wtq, 384, 1152);
    transpose_cvt<<<(384*384  + 255)/256, 256, 0, stream>>>(w_proj, wtp, 384, 384);
    qkv_gemm<<<MTOK_/128, 256, 0, stream>>>(x, wtq, b_qkv, qws, kws, vws);
    attention<<<NW_*HEADS_, 576, 0, stream>>>(qws, kws, vws, btab, pidx, mask, ows);
    proj_gemm<<<MTOK_/128, 256, 0, stream>>>(ows, wtp, b_proj, out);
}